// Round 4
// baseline (2975.004 us; speedup 1.0000x reference)
//
#include <hip/hip_runtime.h>
#include <hip/hip_bf16.h>
#include <math.h>

typedef __bf16 bf16;
typedef __bf16 bf16x8 __attribute__((ext_vector_type(8)));
typedef __bf16 bf16x4 __attribute__((ext_vector_type(4)));
typedef float f32x4 __attribute__((ext_vector_type(4)));

#define NINP 400
#define HS   1000
#define HP   1024
#define B_   8
#define T_   256
#define NT   2048   /* B_*T_ */
#define K2   2048   /* 2*HP  */
#define K1   1024   /* 2*512 */
#define M_   4096   /* 4 gates * HP */

#define HT_OFF   819200
#define CT_OFF   827200
#define AUX_OFF  835200

typedef __attribute__((address_space(1))) const void gvoid;
typedef __attribute__((address_space(3))) void lvoid;

__device__ __forceinline__ void async_copy16(void* lds, const void* g) {
  __builtin_amdgcn_global_load_lds((gvoid*)g, (lvoid*)lds, 16, 0, 0);
}

__device__ __forceinline__ float sigm(float x) { return 1.0f / (1.0f + expf(-x)); }

// ---------------- repack kernels (fp32 inputs -> padded bf16) ----------------

__global__ void repack_w1(const float* __restrict__ w1, bf16* __restrict__ W1p) {
  int idx = blockIdx.x * 256 + threadIdx.x;           // 4096*1024
  if (idx >= M_ * K1) return;
  int gr = idx >> 10, k = idx & 1023;
  int g = gr >> 10, hp = gr & (HP - 1);
  float v = 0.0f;
  if (hp < HS) {
    int c = g * HS + hp;
    if (k < 512) { if (k < NINP) v = w1[(size_t)c * (NINP * 2) + k * 2 + 0]; }
    else { int j = k - 512; if (j < NINP) v = w1[(size_t)c * (NINP * 2) + j * 2 + 1]; }
  }
  W1p[idx] = (bf16)v;
}

__global__ void repack_w2(const float* __restrict__ w2, bf16* __restrict__ W2p) {
  int idx = blockIdx.x * 256 + threadIdx.x;           // 4096*2048
  if (idx >= M_ * K2) return;
  int gr = idx >> 11, k = idx & 2047;
  int g = gr >> 10, hp = gr & (HP - 1);
  float v = 0.0f;
  if (hp < HS) {
    int c = g * HS + hp;
    if (k < HP) { if (k < HS) v = w2[(size_t)c * (HS * 2) + k * 2 + 0]; }
    else { int j = k - HP; if (j < HS) v = w2[(size_t)c * (HS * 2) + j * 2 + 1]; }
  }
  W2p[idx] = (bf16)v;
}

__global__ void build_xt(const float* __restrict__ X, bf16* __restrict__ XT) {
  int idx = blockIdx.x * 256 + threadIdx.x;           // 2048*1024
  if (idx >= NT * K1) return;
  int n = idx >> 10, k = idx & 1023;
  int b = n >> 8, t = n & (T_ - 1);
  float v = 0.0f;
  if (k < 512) { if (k < NINP && t > 0) v = X[((size_t)b * NINP + k) * T_ + t - 1]; }
  else { int j = k - 512; if (j < NINP) v = X[((size_t)b * NINP + j) * T_ + t]; }
  XT[idx] = (bf16)v;
}

__global__ void build_hc(const float* __restrict__ hid, const float* __restrict__ cell,
                         bf16* __restrict__ hidp, float* __restrict__ cellp) {
  int idx = blockIdx.x * 256 + threadIdx.x;           // 8*1024
  if (idx >= B_ * HP) return;
  int b = idx >> 10, k = idx & (HP - 1);
  hidp[idx]  = (k < HS) ? (bf16)hid[b * HS + k] : (bf16)0.0f;
  cellp[idx] = (k < HS) ? cell[b * HS + k] : 0.0f;
}

// ---------------- fused GEMM (+gating) kernel ----------------
// Tile: 128 M x 128 N, BK=64. 4 waves, wave w owns all 128 M rows x cols [32w,32w+32).
// grid (16,32) = 512 blocks = 2/CU. GATED: XCD swizzle so XCD(L&7) sees 4 bm values
// (W2p slice 2 MB + CbP slice 1 MB -> L2-resident).
// CbP layout: [n][hb*64 + g*16 + hh]  (hb = h>>4, hh = h&15) bf16 -- line-aligned
// 128B reads per (n,u) in the gated epilogue.

template <bool GATED>
__global__ __launch_bounds__(256, 2) void gemm_step(
    const bf16* __restrict__ A,      // W2p [M_][K2] or W1p [M_][K1]
    const bf16* __restrict__ Bsrc,   // gated: Hprev [NT][HP]; plain: XT [NT][K1]
    const bf16* __restrict__ hidp,   // [B_][HP]
    const bf16* __restrict__ CbIn,   // gated: CbP [NT][4096]
    bf16* __restrict__ CbOut,        // plain: write CbP
    const float* __restrict__ b2,
    const bf16* __restrict__ ctprev, // [HP][NT] bf16
    const float* __restrict__ cellp, // [B_][HP]
    bf16* __restrict__ ctnew,        // [HP][NT] bf16
    bf16* __restrict__ Hnew,         // [NT][HP]
    int K) {
  __shared__ bf16 As[128][64];   // 16 KB (Csh overlays after K-loop in plain path)
  __shared__ bf16 Bs[128][64];   // 16 KB
  __shared__ bf16 Hsh[128][32];  //  8 KB

  const int tid = threadIdx.x;
  const int w = tid >> 6;
  const int lane = tid & 63;
  const int c8 = lane & 7;   // 16B chunk within 128B row
  const int dr = lane >> 3;  // row within 8-row group
  const int quad = lane >> 4;
  const int col = lane & 15;

  int n0, bm;
  if (GATED) {
    const int L = blockIdx.y * gridDim.x + blockIdx.x;
    bm = (L & 7) * 4 + (L >> 7);      // XCD L&7 owns bm in {4x..4x+3}
    n0 = ((L >> 3) & 15) * 128;
  } else {
    n0 = blockIdx.x * 128;
    bm = blockIdx.y;
  }

  f32x4 acc[8][2];
#pragma unroll
  for (int i = 0; i < 8; ++i)
#pragma unroll
    for (int j = 0; j < 2; ++j) acc[i][j] = (f32x4){0.f, 0.f, 0.f, 0.f};

  for (int k0 = 0; k0 < K; k0 += 64) {
    __syncthreads();
#pragma unroll
    for (int inst = 0; inst < 4; ++inst) {
      const int r = inst * 32 + w * 8 + dr;
      int grow;
      if (GATED) grow = (r >> 5) * HP + bm * 32 + (r & 31);
      else       grow = bm * 128 + r;
      async_copy16(&As[inst * 32 + w * 8][0], A + (size_t)grow * K + k0 + c8 * 8);

      const int n = n0 + r;
      const bf16* bp;
      if (GATED) {
        const int kk = (k0 & (HP - 1)) + c8 * 8;
        if (k0 < HP) {
          const int t = n & (T_ - 1);
          bp = (t == 0) ? (hidp + (size_t)(n >> 8) * HP + kk)
                        : (Bsrc + (size_t)(n - 1) * HP + kk);
        } else {
          bp = Bsrc + (size_t)n * HP + kk;
        }
      } else {
        bp = Bsrc + (size_t)n * K1 + k0 + c8 * 8;
      }
      async_copy16(&Bs[inst * 32 + w * 8][0], bp);
    }
    __syncthreads();
#pragma unroll
    for (int kc = 0; kc < 64; kc += 32) {
      bf16x8 av[8], bv[2];
#pragma unroll
      for (int mt = 0; mt < 8; ++mt)
        av[mt] = *(const bf16x8*)&As[col + 16 * mt][kc + quad * 8];
#pragma unroll
      for (int nt = 0; nt < 2; ++nt)
        bv[nt] = *(const bf16x8*)&Bs[w * 32 + nt * 16 + col][kc + quad * 8];
#pragma unroll
      for (int mt = 0; mt < 8; ++mt)
#pragma unroll
        for (int nt = 0; nt < 2; ++nt)
          acc[mt][nt] = __builtin_amdgcn_mfma_f32_16x16x32_bf16(av[mt], bv[nt], acc[mt][nt], 0, 0, 0);
    }
  }

  if (!GATED) {
    // Write CbP = conv1+bias, bf16, gate-interleaved: CbP[n][hb*64+g*16+hh].
    // Block's M rows: grow = bm*128 + mt*16+quad*4+reg -> g=bm>>3, hb=(bm&7)*8+mt.
    bf16 (*Csh)[16] = (bf16(*)[16])&As[0][0];  // 4 KB overlay on dead As
    const int g = bm >> 3;
#pragma unroll
    for (int mt = 0; mt < 8; ++mt) {
      __syncthreads();
#pragma unroll
      for (int nt = 0; nt < 2; ++nt) {
        const int nl = w * 32 + nt * 16 + col;
#pragma unroll
        for (int reg = 0; reg < 4; ++reg) {
          const int hp = (bm & 7) * 128 + mt * 16 + quad * 4 + reg;
          const float bias = (hp < HS) ? b2[g * HS + hp] : 0.0f;
          Csh[nl][quad * 4 + reg] = (bf16)(acc[mt][nt][reg] + bias);
        }
      }
      __syncthreads();
      const int colbase = ((bm & 7) * 8 + mt) * 64 + g * 16;
      const int row = tid >> 1, half = tid & 1;
      *(bf16x8*)&CbOut[(size_t)(n0 + row) * 4096 + colbase + half * 8] =
          *(const bf16x8*)&Csh[row][half * 8];
    }
  } else {
    const int h0 = bm * 32;
#pragma unroll
    for (int u = 0; u < 2; ++u) {
#pragma unroll
      for (int nt = 0; nt < 2; ++nt) {
        const int nl = w * 32 + nt * 16 + col;
        const int n = n0 + nl;
        const int b = n >> 8;
        const int t = n & (T_ - 1);
        const size_t cbase = (size_t)n * 4096 + (size_t)(bm * 2 + u) * 64 + quad * 4;
        bf16x4 cb0 = *(const bf16x4*)&CbIn[cbase + 0 * 16];
        bf16x4 cb1 = *(const bf16x4*)&CbIn[cbase + 1 * 16];
        bf16x4 cb2 = *(const bf16x4*)&CbIn[cbase + 2 * 16];
        bf16x4 cb3 = *(const bf16x4*)&CbIn[cbase + 3 * 16];
#pragma unroll
        for (int reg = 0; reg < 4; ++reg) {
          const int hh = u * 16 + quad * 4 + reg;
          const int h = h0 + hh;
          const float ci = acc[0 + u][nt][reg] + (float)cb0[reg];
          const float co = acc[2 + u][nt][reg] + (float)cb1[reg];
          const float cg = acc[4 + u][nt][reg] + (float)cb2[reg];
          const float cf = acc[6 + u][nt][reg] + (float)cb3[reg];
          const float ctold = (t == 0) ? cellp[b * HP + h]
                                       : (float)ctprev[(size_t)h * NT + (n - 1)];
          const float cn = sigm(cf) * ctold + sigm(ci) * tanhf(cg);
          ctnew[(size_t)h * NT + n] = (bf16)cn;
          Hsh[nl][hh] = (bf16)(sigm(co) * tanhf(cn));
        }
      }
    }
    __syncthreads();
#pragma unroll
    for (int it2 = 0; it2 < 4; ++it2) {
      const int idx = it2 * 256 + tid;  // 1024 chunks of 4 bf16
      const int row = idx >> 3;
      const int c4 = idx & 7;
      *(bf16x4*)&Hnew[(size_t)(n0 + row) * HP + h0 + c4 * 4] =
          *(const bf16x4*)&Hsh[row][c4 * 4];
    }
  }
}

// ---------------- output kernels (fp32 out) ----------------

__global__ void aux_kernel(const bf16* __restrict__ H, float* __restrict__ out, int s) {
  int idx = blockIdx.x * 256 + threadIdx.x;  // 8*256*100
  if (idx >= NT * 100) return;
  int n = idx / 100;
  int o = (idx % 100) * 4;
  int b = n >> 8, t = n & (T_ - 1);
  bf16x4 v = *(const bf16x4*)&H[(size_t)n * HP + 600 + o];
  f32x4 f = {(float)v[0], (float)v[1], (float)v[2], (float)v[3]};
  *(f32x4*)&out[AUX_OFF + ((size_t)((b * 2 + s) * T_ + t)) * 400 + o] = f;
}

__global__ void final_kernel(const bf16* __restrict__ H, const bf16* __restrict__ ct,
                             float* __restrict__ out) {
  int idx = blockIdx.x * 256 + threadIdx.x;
  if (idx < NT * 100) {
    int n = idx / 100;
    int o = (idx % 100) * 4;
    int b = n >> 8, t = n & (T_ - 1);
    bf16x4 v = *(const bf16x4*)&H[(size_t)n * HP + 600 + o];
    f32x4 f = {(float)v[0], (float)v[1], (float)v[2], (float)v[3]};
    *(f32x4*)&out[(size_t)n * 400 + o] = f;  // out_main [b][t][400]
    *(f32x4*)&out[AUX_OFF + ((size_t)((b * 2 + 1) * T_ + t)) * 400 + o] = f;
  } else {
    int j = idx - NT * 100;
    if (j < 8000) {
      int b = j / 1000, h = j % 1000;
      out[HT_OFF + j] = (float)H[(size_t)(b * T_ + 255) * HP + h];
    } else if (j < 16000) {
      int jj = j - 8000;
      int b = jj / 1000, h = jj % 1000;
      out[CT_OFF + jj] = (float)ct[(size_t)h * NT + b * T_ + 255];
    }
  }
}

// ---------------- launch ----------------

extern "C" void kernel_launch(void* const* d_in, const int* in_sizes, int n_in,
                              void* d_out, int out_size, void* d_ws, size_t ws_size,
                              hipStream_t stream) {
  const float* X    = (const float*)d_in[0];
  const float* hid  = (const float*)d_in[1];
  const float* cell = (const float*)d_in[2];
  const float* w1   = (const float*)d_in[3];
  const float* w2   = (const float*)d_in[4];
  const float* b2   = (const float*)d_in[5];
  float* out = (float*)d_out;

  char* ws = (char*)d_ws;
  size_t off = 0;
  auto alloc = [&](size_t bytes) {
    void* p = ws + off;
    off += (bytes + 255) & ~(size_t)255;
    return p;
  };
  bf16* W2p    = (bf16*)alloc((size_t)M_ * K2 * 2);     // 16 MB
  bf16* CbP    = (bf16*)alloc((size_t)NT * M_ * 2);     // 16 MB
  bf16* Hb0    = (bf16*)alloc((size_t)NT * HP * 2);     // 4 MB
  bf16* ctb0   = (bf16*)alloc((size_t)HP * NT * 2);     // 4 MB
  bf16* hidp   = (bf16*)alloc((size_t)B_ * HP * 2);
  float* cellp = (float*)alloc((size_t)B_ * HP * 4);
  // Union region: {W1p, XT} live only until the first GEMM; then {ctb1, Hb1}.
  char* R = (char*)alloc((size_t)12 * 1024 * 1024);     // 12 MB
  bf16* W1p  = (bf16*)R;                                // 8 MB
  bf16* XT   = (bf16*)(R + (size_t)8 * 1024 * 1024);    // 4 MB
  bf16* ctb1 = (bf16*)R;                                // 4 MB
  bf16* Hb1  = (bf16*)(R + (size_t)4 * 1024 * 1024);    // 4 MB

  bf16* Hb[2]  = {Hb0, Hb1};
  bf16* ctb[2] = {ctb0, ctb1};

  hipMemsetAsync(Hb[0], 0, (size_t)NT * HP * 2, stream);
  hipMemsetAsync(ctb[0], 0, (size_t)HP * NT * 2, stream);

  repack_w1<<<(M_ * K1) / 256, 256, 0, stream>>>(w1, W1p);
  repack_w2<<<(M_ * K2) / 256, 256, 0, stream>>>(w2, W2p);
  build_xt<<<(NT * K1) / 256, 256, 0, stream>>>(X, XT);
  build_hc<<<(B_ * HP) / 256, 256, 0, stream>>>(hid, cell, hidp, cellp);

  dim3 grid(NT / 128, 32);  // 16 x 32 = 512 blocks, 2/CU
  gemm_step<false><<<grid, 256, 0, stream>>>(W1p, XT, nullptr, nullptr, CbP, b2,
                                             nullptr, nullptr, nullptr, nullptr, K1);
  for (int i = 0; i < 40; ++i) {
    int p = i & 1;
    gemm_step<true><<<grid, 256, 0, stream>>>(W2p, Hb[p], hidp, CbP, nullptr, nullptr,
                                              ctb[p], cellp, ctb[p ^ 1], Hb[p ^ 1], K2);
    if (i == 19) aux_kernel<<<800, 256, 0, stream>>>(Hb[p ^ 1], out, 0);
  }
  final_kernel<<<(NT * 100 + 16000 + 255) / 256, 256, 0, stream>>>(Hb[0], ctb[0], out);
}

// Round 5
// 2110.907 us; speedup vs baseline: 1.4093x; 1.4093x over previous
//
#include <hip/hip_runtime.h>
#include <hip/hip_bf16.h>
#include <math.h>

typedef __bf16 bf16;
typedef __bf16 bf16x8 __attribute__((ext_vector_type(8)));
typedef __bf16 bf16x4 __attribute__((ext_vector_type(4)));
typedef float f32x4 __attribute__((ext_vector_type(4)));

#define NINP 400
#define HS   1000
#define HP   1024
#define B_   8
#define T_   256
#define NT   2048   /* B_*T_ */
#define K2   2048   /* 2*HP  */
#define K1   1024   /* 2*512 */
#define M_   4096   /* 4 gates * HP */

#define HT_OFF   819200
#define CT_OFF   827200
#define AUX_OFF  835200

typedef __attribute__((address_space(1))) const void gvoid;
typedef __attribute__((address_space(3))) void lvoid;

__device__ __forceinline__ void async_copy16(void* lds, const void* g) {
  __builtin_amdgcn_global_load_lds((gvoid*)g, (lvoid*)lds, 16, 0, 0);
}

__device__ __forceinline__ float sigm(float x) { return 1.0f / (1.0f + expf(-x)); }

// ---------------- repack kernels (fp32 inputs -> padded bf16) ----------------

__global__ void repack_w1(const float* __restrict__ w1, bf16* __restrict__ W1p) {
  int idx = blockIdx.x * 256 + threadIdx.x;           // 4096*1024
  if (idx >= M_ * K1) return;
  int gr = idx >> 10, k = idx & 1023;
  int g = gr >> 10, hp = gr & (HP - 1);
  float v = 0.0f;
  if (hp < HS) {
    int c = g * HS + hp;
    if (k < 512) { if (k < NINP) v = w1[(size_t)c * (NINP * 2) + k * 2 + 0]; }
    else { int j = k - 512; if (j < NINP) v = w1[(size_t)c * (NINP * 2) + j * 2 + 1]; }
  }
  W1p[idx] = (bf16)v;
}

__global__ void repack_w2(const float* __restrict__ w2, bf16* __restrict__ W2p) {
  int idx = blockIdx.x * 256 + threadIdx.x;           // 4096*2048
  if (idx >= M_ * K2) return;
  int gr = idx >> 11, k = idx & 2047;
  int g = gr >> 10, hp = gr & (HP - 1);
  float v = 0.0f;
  if (hp < HS) {
    int c = g * HS + hp;
    if (k < HP) { if (k < HS) v = w2[(size_t)c * (HS * 2) + k * 2 + 0]; }
    else { int j = k - HP; if (j < HS) v = w2[(size_t)c * (HS * 2) + j * 2 + 1]; }
  }
  W2p[idx] = (bf16)v;
}

__global__ void build_xt(const float* __restrict__ X, bf16* __restrict__ XT) {
  int idx = blockIdx.x * 256 + threadIdx.x;           // 2048*1024
  if (idx >= NT * K1) return;
  int n = idx >> 10, k = idx & 1023;
  int b = n >> 8, t = n & (T_ - 1);
  float v = 0.0f;
  if (k < 512) { if (k < NINP && t > 0) v = X[((size_t)b * NINP + k) * T_ + t - 1]; }
  else { int j = k - 512; if (j < NINP) v = X[((size_t)b * NINP + j) * T_ + t]; }
  XT[idx] = (bf16)v;
}

__global__ void build_hc(const float* __restrict__ hid, const float* __restrict__ cell,
                         bf16* __restrict__ hidp, float* __restrict__ cellp) {
  int idx = blockIdx.x * 256 + threadIdx.x;           // 8*1024
  if (idx >= B_ * HP) return;
  int b = idx >> 10, k = idx & (HP - 1);
  hidp[idx]  = (k < HS) ? (bf16)hid[b * HS + k] : (bf16)0.0f;
  cellp[idx] = (k < HS) ? cell[b * HS + k] : 0.0f;
}

// ---------------- fused GEMM (+gating) kernel ----------------
// Tile: 128 M x 128 N, BK=64. 4 waves, wave w owns all 128 M rows x cols [32w,32w+32).
// LDS chunk-rotation swizzle: row r's logical 16B chunk l lives at phys chunk
// (l + r) & 7. Staging achieves this by reading global offset ((c8 - dr)&7)*8
// (global_load_lds LDS dst is fixed wave-uniform+lane*16, so we permute the
// SOURCE). Fragment reads rotate by ((kc>>3)+quad+row)&7 -> 2-way bank
// aliasing (free, m136) instead of 16-way.

template <bool GATED>
__global__ __launch_bounds__(256, 2) void gemm_step(
    const bf16* __restrict__ A,      // W2p [M_][K2] or W1p [M_][K1]
    const bf16* __restrict__ Bsrc,   // gated: Hprev [NT][HP]; plain: XT [NT][K1]
    const bf16* __restrict__ hidp,   // [B_][HP]
    const bf16* __restrict__ CbIn,   // gated: CbP [NT][4096]
    bf16* __restrict__ CbOut,        // plain: write CbP
    const float* __restrict__ b2,
    const bf16* __restrict__ ctprev, // [HP][NT] bf16
    const float* __restrict__ cellp, // [B_][HP]
    bf16* __restrict__ ctnew,        // [HP][NT] bf16
    bf16* __restrict__ Hnew,         // [NT][HP]
    int K) {
  __shared__ bf16 As[128][64];   // 16 KB (Csh overlays after K-loop in plain path)
  __shared__ bf16 Bs[128][64];   // 16 KB
  __shared__ bf16 Hsh[128][32];  //  8 KB

  const int tid = threadIdx.x;
  const int w = tid >> 6;
  const int lane = tid & 63;
  const int c8 = lane & 7;   // 16B chunk within 128B row
  const int dr = lane >> 3;  // row within 8-row group
  const int quad = lane >> 4;
  const int col = lane & 15;
  const int swo = ((c8 - dr) & 7) * 8;  // swizzled global k-offset for staging

  int n0, bm;
  if (GATED) {
    const int L = blockIdx.y * gridDim.x + blockIdx.x;
    bm = (L & 7) * 4 + (L >> 7);      // XCD L&7 owns bm in {4x..4x+3}
    n0 = ((L >> 3) & 15) * 128;
  } else {
    n0 = blockIdx.x * 128;
    bm = blockIdx.y;
  }

  f32x4 acc[8][2];
#pragma unroll
  for (int i = 0; i < 8; ++i)
#pragma unroll
    for (int j = 0; j < 2; ++j) acc[i][j] = (f32x4){0.f, 0.f, 0.f, 0.f};

  for (int k0 = 0; k0 < K; k0 += 64) {
    __syncthreads();
#pragma unroll
    for (int inst = 0; inst < 4; ++inst) {
      const int r = inst * 32 + w * 8 + dr;
      int grow;
      if (GATED) grow = (r >> 5) * HP + bm * 32 + (r & 31);
      else       grow = bm * 128 + r;
      async_copy16(&As[inst * 32 + w * 8][0], A + (size_t)grow * K + k0 + swo);

      const int n = n0 + r;
      const bf16* bp;
      if (GATED) {
        const int kk = (k0 & (HP - 1)) + swo;
        if (k0 < HP) {
          const int t = n & (T_ - 1);
          bp = (t == 0) ? (hidp + (size_t)(n >> 8) * HP + kk)
                        : (Bsrc + (size_t)(n - 1) * HP + kk);
        } else {
          bp = Bsrc + (size_t)n * HP + kk;
        }
      } else {
        bp = Bsrc + (size_t)n * K1 + k0 + swo;
      }
      async_copy16(&Bs[inst * 32 + w * 8][0], bp);
    }
    __syncthreads();
#pragma unroll
    for (int kc = 0; kc < 64; kc += 32) {
      bf16x8 av[8], bv[2];
#pragma unroll
      for (int mt = 0; mt < 8; ++mt) {
        const int rA = col + 16 * mt;
        av[mt] = *(const bf16x8*)&As[rA][(((kc >> 3) + quad + rA) & 7) * 8];
      }
#pragma unroll
      for (int nt = 0; nt < 2; ++nt) {
        const int rB = w * 32 + nt * 16 + col;
        bv[nt] = *(const bf16x8*)&Bs[rB][(((kc >> 3) + quad + rB) & 7) * 8];
      }
#pragma unroll
      for (int mt = 0; mt < 8; ++mt)
#pragma unroll
        for (int nt = 0; nt < 2; ++nt)
          acc[mt][nt] = __builtin_amdgcn_mfma_f32_16x16x32_bf16(av[mt], bv[nt], acc[mt][nt], 0, 0, 0);
    }
  }

  if (!GATED) {
    // Write CbP = conv1+bias, bf16, gate-interleaved: CbP[n][hb*64+g*16+hh].
    bf16 (*Csh)[16] = (bf16(*)[16])&As[0][0];  // 4 KB overlay on dead As
    const int g = bm >> 3;
#pragma unroll
    for (int mt = 0; mt < 8; ++mt) {
      __syncthreads();
#pragma unroll
      for (int nt = 0; nt < 2; ++nt) {
        const int nl = w * 32 + nt * 16 + col;
#pragma unroll
        for (int reg = 0; reg < 4; ++reg) {
          const int hp = (bm & 7) * 128 + mt * 16 + quad * 4 + reg;
          const float bias = (hp < HS) ? b2[g * HS + hp] : 0.0f;
          Csh[nl][quad * 4 + reg] = (bf16)(acc[mt][nt][reg] + bias);
        }
      }
      __syncthreads();
      const int colbase = ((bm & 7) * 8 + mt) * 64 + g * 16;
      const int row = tid >> 1, half = tid & 1;
      *(bf16x8*)&CbOut[(size_t)(n0 + row) * 4096 + colbase + half * 8] =
          *(const bf16x8*)&Csh[row][half * 8];
    }
  } else {
    const int h0 = bm * 32;
#pragma unroll
    for (int u = 0; u < 2; ++u) {
#pragma unroll
      for (int nt = 0; nt < 2; ++nt) {
        const int nl = w * 32 + nt * 16 + col;
        const int n = n0 + nl;
        const int b = n >> 8;
        const int t = n & (T_ - 1);
        const size_t cbase = (size_t)n * 4096 + (size_t)(bm * 2 + u) * 64 + quad * 4;
        bf16x4 cb0 = *(const bf16x4*)&CbIn[cbase + 0 * 16];
        bf16x4 cb1 = *(const bf16x4*)&CbIn[cbase + 1 * 16];
        bf16x4 cb2 = *(const bf16x4*)&CbIn[cbase + 2 * 16];
        bf16x4 cb3 = *(const bf16x4*)&CbIn[cbase + 3 * 16];
#pragma unroll
        for (int reg = 0; reg < 4; ++reg) {
          const int hh = u * 16 + quad * 4 + reg;
          const int h = h0 + hh;
          const float ci = acc[0 + u][nt][reg] + (float)cb0[reg];
          const float co = acc[2 + u][nt][reg] + (float)cb1[reg];
          const float cg = acc[4 + u][nt][reg] + (float)cb2[reg];
          const float cf = acc[6 + u][nt][reg] + (float)cb3[reg];
          const float ctold = (t == 0) ? cellp[b * HP + h]
                                       : (float)ctprev[(size_t)h * NT + (n - 1)];
          const float cn = sigm(cf) * ctold + sigm(ci) * tanhf(cg);
          ctnew[(size_t)h * NT + n] = (bf16)cn;
          Hsh[nl][hh] = (bf16)(sigm(co) * tanhf(cn));
        }
      }
    }
    __syncthreads();
#pragma unroll
    for (int it2 = 0; it2 < 4; ++it2) {
      const int idx = it2 * 256 + tid;  // 1024 chunks of 4 bf16
      const int row = idx >> 3;
      const int c4 = idx & 7;
      *(bf16x4*)&Hnew[(size_t)(n0 + row) * HP + h0 + c4 * 4] =
          *(const bf16x4*)&Hsh[row][c4 * 4];
    }
  }
}

// ---------------- output kernels (fp32 out) ----------------

__global__ void aux_kernel(const bf16* __restrict__ H, float* __restrict__ out, int s) {
  int idx = blockIdx.x * 256 + threadIdx.x;  // 8*256*100
  if (idx >= NT * 100) return;
  int n = idx / 100;
  int o = (idx % 100) * 4;
  int b = n >> 8, t = n & (T_ - 1);
  bf16x4 v = *(const bf16x4*)&H[(size_t)n * HP + 600 + o];
  f32x4 f = {(float)v[0], (float)v[1], (float)v[2], (float)v[3]};
  *(f32x4*)&out[AUX_OFF + ((size_t)((b * 2 + s) * T_ + t)) * 400 + o] = f;
}

__global__ void final_kernel(const bf16* __restrict__ H, const bf16* __restrict__ ct,
                             float* __restrict__ out) {
  int idx = blockIdx.x * 256 + threadIdx.x;
  if (idx < NT * 100) {
    int n = idx / 100;
    int o = (idx % 100) * 4;
    int b = n >> 8, t = n & (T_ - 1);
    bf16x4 v = *(const bf16x4*)&H[(size_t)n * HP + 600 + o];
    f32x4 f = {(float)v[0], (float)v[1], (float)v[2], (float)v[3]};
    *(f32x4*)&out[(size_t)n * 400 + o] = f;  // out_main [b][t][400]
    *(f32x4*)&out[AUX_OFF + ((size_t)((b * 2 + 1) * T_ + t)) * 400 + o] = f;
  } else {
    int j = idx - NT * 100;
    if (j < 8000) {
      int b = j / 1000, h = j % 1000;
      out[HT_OFF + j] = (float)H[(size_t)(b * T_ + 255) * HP + h];
    } else if (j < 16000) {
      int jj = j - 8000;
      int b = jj / 1000, h = jj % 1000;
      out[CT_OFF + jj] = (float)ct[(size_t)h * NT + b * T_ + 255];
    }
  }
}

// ---------------- launch ----------------

extern "C" void kernel_launch(void* const* d_in, const int* in_sizes, int n_in,
                              void* d_out, int out_size, void* d_ws, size_t ws_size,
                              hipStream_t stream) {
  const float* X    = (const float*)d_in[0];
  const float* hid  = (const float*)d_in[1];
  const float* cell = (const float*)d_in[2];
  const float* w1   = (const float*)d_in[3];
  const float* w2   = (const float*)d_in[4];
  const float* b2   = (const float*)d_in[5];
  float* out = (float*)d_out;

  char* ws = (char*)d_ws;
  size_t off = 0;
  auto alloc = [&](size_t bytes) {
    void* p = ws + off;
    off += (bytes + 255) & ~(size_t)255;
    return p;
  };
  bf16* W2p    = (bf16*)alloc((size_t)M_ * K2 * 2);     // 16 MB
  bf16* CbP    = (bf16*)alloc((size_t)NT * M_ * 2);     // 16 MB
  bf16* Hb0    = (bf16*)alloc((size_t)NT * HP * 2);     // 4 MB
  bf16* ctb0   = (bf16*)alloc((size_t)HP * NT * 2);     // 4 MB
  bf16* hidp   = (bf16*)alloc((size_t)B_ * HP * 2);
  float* cellp = (float*)alloc((size_t)B_ * HP * 4);
  // Union region: {W1p, XT} live only until the first GEMM; then {ctb1, Hb1}.
  char* R = (char*)alloc((size_t)12 * 1024 * 1024);     // 12 MB
  bf16* W1p  = (bf16*)R;                                // 8 MB
  bf16* XT   = (bf16*)(R + (size_t)8 * 1024 * 1024);    // 4 MB
  bf16* ctb1 = (bf16*)R;                                // 4 MB
  bf16* Hb1  = (bf16*)(R + (size_t)4 * 1024 * 1024);    // 4 MB

  bf16* Hb[2]  = {Hb0, Hb1};
  bf16* ctb[2] = {ctb0, ctb1};

  hipMemsetAsync(Hb[0], 0, (size_t)NT * HP * 2, stream);
  hipMemsetAsync(ctb[0], 0, (size_t)HP * NT * 2, stream);

  repack_w1<<<(M_ * K1) / 256, 256, 0, stream>>>(w1, W1p);
  repack_w2<<<(M_ * K2) / 256, 256, 0, stream>>>(w2, W2p);
  build_xt<<<(NT * K1) / 256, 256, 0, stream>>>(X, XT);
  build_hc<<<(B_ * HP) / 256, 256, 0, stream>>>(hid, cell, hidp, cellp);

  dim3 grid(NT / 128, 32);  // 16 x 32 = 512 blocks, 2/CU
  gemm_step<false><<<grid, 256, 0, stream>>>(W1p, XT, nullptr, nullptr, CbP, b2,
                                             nullptr, nullptr, nullptr, nullptr, K1);
  for (int i = 0; i < 40; ++i) {
    int p = i & 1;
    gemm_step<true><<<grid, 256, 0, stream>>>(W2p, Hb[p], hidp, CbP, nullptr, nullptr,
                                              ctb[p], cellp, ctb[p ^ 1], Hb[p ^ 1], K2);
    if (i == 19) aux_kernel<<<800, 256, 0, stream>>>(Hb[p ^ 1], out, 0);
  }
  final_kernel<<<(NT * 100 + 16000 + 255) / 256, 256, 0, stream>>>(Hb[0], ctb[0], out);
}

// Round 6
// 2013.511 us; speedup vs baseline: 1.4775x; 1.0484x over previous
//
#include <hip/hip_runtime.h>
#include <hip/hip_bf16.h>
#include <math.h>

typedef __bf16 bf16;
typedef __bf16 bf16x8 __attribute__((ext_vector_type(8)));
typedef __bf16 bf16x4 __attribute__((ext_vector_type(4)));
typedef float f32x4 __attribute__((ext_vector_type(4)));

#define NINP 400
#define HS   1000
#define HP   1024
#define B_   8
#define T_   256
#define NT   2048   /* B_*T_ */
#define K2   2048   /* 2*HP  */
#define K1   1024   /* 2*512 */
#define M_   4096   /* 4 gates * HP */

#define HT_OFF   819200
#define CT_OFF   827200
#define AUX_OFF  835200

typedef __attribute__((address_space(1))) const void gvoid;
typedef __attribute__((address_space(3))) void lvoid;

__device__ __forceinline__ void async_copy16(void* lds, const void* g) {
  __builtin_amdgcn_global_load_lds((gvoid*)g, (lvoid*)lds, 16, 0, 0);
}

__device__ __forceinline__ float sigm(float x) { return 1.0f / (1.0f + expf(-x)); }

// ---------------- repack kernels (fp32 inputs -> padded bf16) ----------------

__global__ void repack_w1(const float* __restrict__ w1, bf16* __restrict__ W1p) {
  int idx = blockIdx.x * 256 + threadIdx.x;           // 4096*1024
  if (idx >= M_ * K1) return;
  int gr = idx >> 10, k = idx & 1023;
  int g = gr >> 10, hp = gr & (HP - 1);
  float v = 0.0f;
  if (hp < HS) {
    int c = g * HS + hp;
    if (k < 512) { if (k < NINP) v = w1[(size_t)c * (NINP * 2) + k * 2 + 0]; }
    else { int j = k - 512; if (j < NINP) v = w1[(size_t)c * (NINP * 2) + j * 2 + 1]; }
  }
  W1p[idx] = (bf16)v;
}

__global__ void repack_w2(const float* __restrict__ w2, bf16* __restrict__ W2p) {
  int idx = blockIdx.x * 256 + threadIdx.x;           // 4096*2048
  if (idx >= M_ * K2) return;
  int gr = idx >> 11, k = idx & 2047;
  int g = gr >> 10, hp = gr & (HP - 1);
  float v = 0.0f;
  if (hp < HS) {
    int c = g * HS + hp;
    if (k < HP) { if (k < HS) v = w2[(size_t)c * (HS * 2) + k * 2 + 0]; }
    else { int j = k - HP; if (j < HS) v = w2[(size_t)c * (HS * 2) + j * 2 + 1]; }
  }
  W2p[idx] = (bf16)v;
}

__global__ void build_xt(const float* __restrict__ X, bf16* __restrict__ XT) {
  int idx = blockIdx.x * 256 + threadIdx.x;           // 2048*1024
  if (idx >= NT * K1) return;
  int n = idx >> 10, k = idx & 1023;
  int b = n >> 8, t = n & (T_ - 1);
  float v = 0.0f;
  if (k < 512) { if (k < NINP && t > 0) v = X[((size_t)b * NINP + k) * T_ + t - 1]; }
  else { int j = k - 512; if (j < NINP) v = X[((size_t)b * NINP + j) * T_ + t]; }
  XT[idx] = (bf16)v;
}

__global__ void build_hc(const float* __restrict__ hid, const float* __restrict__ cell,
                         bf16* __restrict__ hidp, float* __restrict__ cellp) {
  int idx = blockIdx.x * 256 + threadIdx.x;           // 8*1024
  if (idx >= B_ * HP) return;
  int b = idx >> 10, k = idx & (HP - 1);
  hidp[idx]  = (k < HS) ? (bf16)hid[b * HS + k] : (bf16)0.0f;
  cellp[idx] = (k < HS) ? cell[b * HS + k] : 0.0f;
}

// ---------------- fused GEMM (+gating) kernel ----------------
// Tile: 64 M x 128 N, BK=64. 4 waves; wave w owns all 64 M rows x cols [32w,32w+32)
// (4 A-frag + 2 B-frag ds_read_b128 per 16 MFMA -- best LDS-read/FLOP ratio).
// grid (16,64) = 1024 blocks = 4/CU. LDS chunk-rotation swizzle (round-5): row r's
// logical 16B chunk l at phys chunk (l+r)&7; staging permutes the GLOBAL source
// offset; fragment reads rotate -> 2-way bank aliasing (free).
// GATED: M rows = 4 gates x 16 hidden (gate = r>>4); XCD swizzle: XCD L&7 owns
// bm in {8x..8x+7} (2 MB W2p slice -> L2-resident).
// CbP layout: [n][hb*64 + g*16 + hh] (hb=h>>4=bm, hh=h&15) -> gated block reads
// one contiguous 128 B line per n.

template <bool GATED>
__global__ __launch_bounds__(256, 4) void gemm_step(
    const bf16* __restrict__ A,      // W2p [M_][K2] or W1p [M_][K1]
    const bf16* __restrict__ Bsrc,   // gated: Hprev [NT][HP]; plain: XT [NT][K1]
    const bf16* __restrict__ hidp,   // [B_][HP]
    const bf16* __restrict__ CbIn,   // gated: CbP [NT][4096]
    bf16* __restrict__ CbOut,        // plain: write CbP
    const float* __restrict__ b2,
    const bf16* __restrict__ ctprev, // [HP][NT] bf16
    const float* __restrict__ cellp, // [B_][HP]
    bf16* __restrict__ ctnew,        // [HP][NT] bf16
    bf16* __restrict__ Hnew,         // [NT][HP]
    int K) {
  __shared__ bf16 As[64][64];    //  8 KB (Hsh/Csh overlay after K-loop)
  __shared__ bf16 Bs[128][64];   // 16 KB

  const int tid = threadIdx.x;
  const int w = tid >> 6;
  const int lane = tid & 63;
  const int c8 = lane & 7;   // 16B chunk within 128B row
  const int dr = lane >> 3;  // row within 8-row group
  const int quad = lane >> 4;
  const int col = lane & 15;
  const int swo = ((c8 - dr) & 7) * 8;  // swizzled global k-offset for staging

  int n0, bm;
  if (GATED) {
    const int L = blockIdx.y * gridDim.x + blockIdx.x;
    bm = (L & 7) * 8 + (L >> 7);      // XCD L&7 owns bm in {8x..8x+7}
    n0 = ((L >> 3) & 15) * 128;
  } else {
    n0 = blockIdx.x * 128;
    bm = blockIdx.y;
  }

  f32x4 acc[4][2];
#pragma unroll
  for (int i = 0; i < 4; ++i)
#pragma unroll
    for (int j = 0; j < 2; ++j) acc[i][j] = (f32x4){0.f, 0.f, 0.f, 0.f};

  for (int k0 = 0; k0 < K; k0 += 64) {
    __syncthreads();
    // ---- A staging: 64 rows (2 wave-chunks of 8 rows)
#pragma unroll
    for (int inst = 0; inst < 2; ++inst) {
      const int r = inst * 32 + w * 8 + dr;
      int grow;
      if (GATED) grow = (r >> 4) * HP + bm * 16 + (r & 15);
      else       grow = bm * 64 + r;
      async_copy16(&As[inst * 32 + w * 8][0], A + (size_t)grow * K + k0 + swo);
    }
    // ---- B staging: 128 rows (4 wave-chunks)
#pragma unroll
    for (int inst = 0; inst < 4; ++inst) {
      const int r = inst * 32 + w * 8 + dr;
      const int n = n0 + r;
      const bf16* bp;
      if (GATED) {
        const int kk = (k0 & (HP - 1)) + swo;
        if (k0 < HP) {
          const int t = n & (T_ - 1);
          bp = (t == 0) ? (hidp + (size_t)(n >> 8) * HP + kk)
                        : (Bsrc + (size_t)(n - 1) * HP + kk);
        } else {
          bp = Bsrc + (size_t)n * HP + kk;
        }
      } else {
        bp = Bsrc + (size_t)n * K1 + k0 + swo;
      }
      async_copy16(&Bs[inst * 32 + w * 8][0], bp);
    }
    __syncthreads();
#pragma unroll
    for (int kc = 0; kc < 64; kc += 32) {
      bf16x8 av[4], bv[2];
#pragma unroll
      for (int mt = 0; mt < 4; ++mt) {
        const int rA = mt * 16 + col;
        av[mt] = *(const bf16x8*)&As[rA][(((kc >> 3) + quad + rA) & 7) * 8];
      }
#pragma unroll
      for (int nt = 0; nt < 2; ++nt) {
        const int rB = w * 32 + nt * 16 + col;
        bv[nt] = *(const bf16x8*)&Bs[rB][(((kc >> 3) + quad + rB) & 7) * 8];
      }
#pragma unroll
      for (int mt = 0; mt < 4; ++mt)
#pragma unroll
        for (int nt = 0; nt < 2; ++nt)
          acc[mt][nt] = __builtin_amdgcn_mfma_f32_16x16x32_bf16(av[mt], bv[nt], acc[mt][nt], 0, 0, 0);
    }
  }

  if (!GATED) {
    // Write CbP = conv1+bias, gate-interleaved: col = hb*64 + g*16 + hh.
    // Block rows: grow = bm*64 + mt*16+quad*4+reg -> g = grow>>10, hp = grow&1023,
    // hb = (bm&15)*4+mt, hh = quad*4+reg.
    bf16 (*Csh)[16] = (bf16(*)[16])&As[0][0];  // 4 KB overlay on dead As
    const int g = (bm * 64) >> 10;
#pragma unroll
    for (int mt = 0; mt < 4; ++mt) {
      __syncthreads();
#pragma unroll
      for (int nt = 0; nt < 2; ++nt) {
        const int nl = w * 32 + nt * 16 + col;
#pragma unroll
        for (int reg = 0; reg < 4; ++reg) {
          const int hp = (bm & 15) * 64 + mt * 16 + quad * 4 + reg;
          const float bias = (hp < HS) ? b2[g * HS + hp] : 0.0f;
          Csh[nl][quad * 4 + reg] = (bf16)(acc[mt][nt][reg] + bias);
        }
      }
      __syncthreads();
      const int colbase = ((bm & 15) * 4 + mt) * 64 + g * 16;
      const int row = tid >> 1, half = tid & 1;
      *(bf16x8*)&CbOut[(size_t)(n0 + row) * 4096 + colbase + half * 8] =
          *(const bf16x8*)&Csh[row][half * 8];
    }
  } else {
    const int h0 = bm * 16;
    bf16 (*Hsh)[16] = (bf16(*)[16])&As[0][0];  // 4 KB overlay on dead As
    __syncthreads();  // all waves done reading As before overlay write
#pragma unroll
    for (int nt = 0; nt < 2; ++nt) {
      const int nl = w * 32 + nt * 16 + col;
      const int n = n0 + nl;
      const int b = n >> 8;
      const int t = n & (T_ - 1);
      const size_t cbase = (size_t)n * 4096 + (size_t)bm * 64 + quad * 4;
      bf16x4 cb0 = *(const bf16x4*)&CbIn[cbase + 0 * 16];
      bf16x4 cb1 = *(const bf16x4*)&CbIn[cbase + 1 * 16];
      bf16x4 cb2 = *(const bf16x4*)&CbIn[cbase + 2 * 16];
      bf16x4 cb3 = *(const bf16x4*)&CbIn[cbase + 3 * 16];
#pragma unroll
      for (int reg = 0; reg < 4; ++reg) {
        const int hh = quad * 4 + reg;
        const int h = h0 + hh;
        const float ci = acc[0][nt][reg] + (float)cb0[reg];
        const float co = acc[1][nt][reg] + (float)cb1[reg];
        const float cg = acc[2][nt][reg] + (float)cb2[reg];
        const float cf = acc[3][nt][reg] + (float)cb3[reg];
        const float ctold = (t == 0) ? cellp[b * HP + h]
                                     : (float)ctprev[(size_t)h * NT + (n - 1)];
        const float cn = sigm(cf) * ctold + sigm(ci) * tanhf(cg);
        ctnew[(size_t)h * NT + n] = (bf16)cn;
        Hsh[nl][hh] = (bf16)(sigm(co) * tanhf(cn));
      }
    }
    __syncthreads();
#pragma unroll
    for (int it2 = 0; it2 < 2; ++it2) {
      const int idx = it2 * 256 + tid;  // 512 chunks of 4 bf16
      const int row = idx >> 2;
      const int c4 = idx & 3;
      *(bf16x4*)&Hnew[(size_t)(n0 + row) * HP + h0 + c4 * 4] =
          *(const bf16x4*)&Hsh[row][c4 * 4];
    }
  }
}

// ---------------- output kernels (fp32 out) ----------------

__global__ void aux_kernel(const bf16* __restrict__ H, float* __restrict__ out, int s) {
  int idx = blockIdx.x * 256 + threadIdx.x;  // 8*256*100
  if (idx >= NT * 100) return;
  int n = idx / 100;
  int o = (idx % 100) * 4;
  int b = n >> 8, t = n & (T_ - 1);
  bf16x4 v = *(const bf16x4*)&H[(size_t)n * HP + 600 + o];
  f32x4 f = {(float)v[0], (float)v[1], (float)v[2], (float)v[3]};
  *(f32x4*)&out[AUX_OFF + ((size_t)((b * 2 + s) * T_ + t)) * 400 + o] = f;
}

__global__ void final_kernel(const bf16* __restrict__ H, const bf16* __restrict__ ct,
                             float* __restrict__ out) {
  int idx = blockIdx.x * 256 + threadIdx.x;
  if (idx < NT * 100) {
    int n = idx / 100;
    int o = (idx % 100) * 4;
    int b = n >> 8, t = n & (T_ - 1);
    bf16x4 v = *(const bf16x4*)&H[(size_t)n * HP + 600 + o];
    f32x4 f = {(float)v[0], (float)v[1], (float)v[2], (float)v[3]};
    *(f32x4*)&out[(size_t)n * 400 + o] = f;  // out_main [b][t][400]
    *(f32x4*)&out[AUX_OFF + ((size_t)((b * 2 + 1) * T_ + t)) * 400 + o] = f;
  } else {
    int j = idx - NT * 100;
    if (j < 8000) {
      int b = j / 1000, h = j % 1000;
      out[HT_OFF + j] = (float)H[(size_t)(b * T_ + 255) * HP + h];
    } else if (j < 16000) {
      int jj = j - 8000;
      int b = jj / 1000, h = jj % 1000;
      out[CT_OFF + jj] = (float)ct[(size_t)h * NT + b * T_ + 255];
    }
  }
}

// ---------------- launch ----------------

extern "C" void kernel_launch(void* const* d_in, const int* in_sizes, int n_in,
                              void* d_out, int out_size, void* d_ws, size_t ws_size,
                              hipStream_t stream) {
  const float* X    = (const float*)d_in[0];
  const float* hid  = (const float*)d_in[1];
  const float* cell = (const float*)d_in[2];
  const float* w1   = (const float*)d_in[3];
  const float* w2   = (const float*)d_in[4];
  const float* b2   = (const float*)d_in[5];
  float* out = (float*)d_out;

  char* ws = (char*)d_ws;
  size_t off = 0;
  auto alloc = [&](size_t bytes) {
    void* p = ws + off;
    off += (bytes + 255) & ~(size_t)255;
    return p;
  };
  bf16* W2p    = (bf16*)alloc((size_t)M_ * K2 * 2);     // 16 MB
  bf16* CbP    = (bf16*)alloc((size_t)NT * M_ * 2);     // 16 MB
  bf16* Hb0    = (bf16*)alloc((size_t)NT * HP * 2);     // 4 MB
  bf16* ctb0   = (bf16*)alloc((size_t)HP * NT * 2);     // 4 MB
  bf16* hidp   = (bf16*)alloc((size_t)B_ * HP * 2);
  float* cellp = (float*)alloc((size_t)B_ * HP * 4);
  // Union region: {W1p, XT} live only until the first GEMM; then {ctb1, Hb1}.
  char* R = (char*)alloc((size_t)12 * 1024 * 1024);     // 12 MB
  bf16* W1p  = (bf16*)R;                                // 8 MB
  bf16* XT   = (bf16*)(R + (size_t)8 * 1024 * 1024);    // 4 MB
  bf16* ctb1 = (bf16*)R;                                // 4 MB
  bf16* Hb1  = (bf16*)(R + (size_t)4 * 1024 * 1024);    // 4 MB

  bf16* Hb[2]  = {Hb0, Hb1};
  bf16* ctb[2] = {ctb0, ctb1};

  hipMemsetAsync(Hb[0], 0, (size_t)NT * HP * 2, stream);
  hipMemsetAsync(ctb[0], 0, (size_t)HP * NT * 2, stream);

  repack_w1<<<(M_ * K1) / 256, 256, 0, stream>>>(w1, W1p);
  repack_w2<<<(M_ * K2) / 256, 256, 0, stream>>>(w2, W2p);
  build_xt<<<(NT * K1) / 256, 256, 0, stream>>>(X, XT);
  build_hc<<<(B_ * HP) / 256, 256, 0, stream>>>(hid, cell, hidp, cellp);

  dim3 grid(NT / 128, M_ / 64);  // 16 x 64 = 1024 blocks = 4/CU
  gemm_step<false><<<grid, 256, 0, stream>>>(W1p, XT, nullptr, nullptr, CbP, b2,
                                             nullptr, nullptr, nullptr, nullptr, K1);
  for (int i = 0; i < 40; ++i) {
    int p = i & 1;
    gemm_step<true><<<grid, 256, 0, stream>>>(W2p, Hb[p], hidp, CbP, nullptr, nullptr,
                                              ctb[p], cellp, ctb[p ^ 1], Hb[p ^ 1], K2);
    if (i == 19) aux_kernel<<<800, 256, 0, stream>>>(Hb[p ^ 1], out, 0);
  }
  final_kernel<<<(NT * 100 + 16000 + 255) / 256, 256, 0, stream>>>(Hb[0], ctb[0], out);
}